// Round 2
// baseline (1955.200 us; speedup 1.0000x reference)
//
#include <hip/hip_runtime.h>
#include <hip/hip_bf16.h>

#define NN 100000
#define NE 1600000
#define NF 32
#define NH 64
#define NH2 128
#define NL 4
#define NG 512
#define BN_EPS 1e-5f

typedef __hip_bfloat16 bf16t;

// ---- storage conversion helpers (h buffer is float or bf16) ----------------
__device__ inline unsigned int f2bfbits(float f) {
    unsigned int x = __float_as_uint(f);
    return (x + 0x7fffu + ((x >> 16) & 1u)) >> 16;  // RNE
}
__device__ inline float ldh(const float* p) { return *p; }
__device__ inline float ldh(const bf16t* p) {
    return __uint_as_float(((unsigned int)*(const unsigned short*)p) << 16);
}
__device__ inline void sth(float* p, float v) { *p = v; }
__device__ inline void sth(bf16t* p, float v) {
    *(unsigned short*)p = (unsigned short)f2bfbits(v);
}
__device__ inline void load8(const float* p, float* o) {
    float4 a = *(const float4*)p, b = *(const float4*)(p + 4);
    o[0] = a.x; o[1] = a.y; o[2] = a.z; o[3] = a.w;
    o[4] = b.x; o[5] = b.y; o[6] = b.z; o[7] = b.w;
}
__device__ inline void load8(const bf16t* p, float* o) {
    uint4 u = *(const uint4*)p;
    o[0] = __uint_as_float(u.x << 16); o[1] = __uint_as_float(u.x & 0xffff0000u);
    o[2] = __uint_as_float(u.y << 16); o[3] = __uint_as_float(u.y & 0xffff0000u);
    o[4] = __uint_as_float(u.z << 16); o[5] = __uint_as_float(u.z & 0xffff0000u);
    o[6] = __uint_as_float(u.w << 16); o[7] = __uint_as_float(u.w & 0xffff0000u);
}
__device__ inline void store8(float* p, const float* v) {
    *(float4*)p = make_float4(v[0], v[1], v[2], v[3]);
    *(float4*)(p + 4) = make_float4(v[4], v[5], v[6], v[7]);
}
__device__ inline void store8(bf16t* p, const float* v) {
    uint4 u;
    u.x = f2bfbits(v[0]) | (f2bfbits(v[1]) << 16);
    u.y = f2bfbits(v[2]) | (f2bfbits(v[3]) << 16);
    u.z = f2bfbits(v[4]) | (f2bfbits(v[5]) << 16);
    u.w = f2bfbits(v[6]) | (f2bfbits(v[7]) << 16);
    *(uint4*)p = u;
}

// ---------------------------------------------------------------------------
// Initial projection: h = x @ W_init + b_init   [N,32]@[32,64]
// ---------------------------------------------------------------------------
template <typename HT>
__global__ __launch_bounds__(256) void k_proj(const float* __restrict__ x,
                                              const float* __restrict__ W,
                                              const float* __restrict__ bias,
                                              HT* __restrict__ h, int N) {
    __shared__ __align__(16) float Ws[NF * NH];
    __shared__ float bs[NH];
    int t = threadIdx.x;
    for (int i = t; i < NF * NH; i += 256) Ws[i] = W[i];
    if (t < NH) bs[t] = bias[t];
    __syncthreads();
    int c = t & 63, gi = t >> 6;
    for (int n = blockIdx.x * 4 + gi; n < N; n += gridDim.x * 4) {
        const float* xr = x + n * NF;
        float acc = bs[c];
#pragma unroll
        for (int k = 0; k < NF; ++k) acc += xr[k] * Ws[k * NH + c];
        sth(&h[(size_t)n * NH + c], acc);
    }
}

// ---------------------------------------------------------------------------
// Edge scatter: S[dst] += h[src]. S pre-zeroed. One wave per edge, lane=channel.
// ---------------------------------------------------------------------------
template <typename HT>
__global__ __launch_bounds__(256) void k_scatter(const HT* __restrict__ h,
                                                 const int* __restrict__ ei,
                                                 float* __restrict__ S, int E) {
    int gid = blockIdx.x * 256 + threadIdx.x;
    int e = gid >> 6;
    int lane = threadIdx.x & 63;
    if (e < E) {
        int src = ei[e];
        int dst = ei[E + e];
        unsafeAtomicAdd(&S[(size_t)dst * NH + lane], ldh(&h[(size_t)src * NH + lane]));
    }
}

// ---------------------------------------------------------------------------
// MLP: m = relu((h+S) @ W1 + b1) @ W2 + b2, m written back INTO S (aliased:
// each tile's rows are fully read into LDS before being overwritten; tiles are
// block-disjoint). Also accumulates BN partial sums.
// ---------------------------------------------------------------------------
template <typename HT>
__global__ __launch_bounds__(256) void k_mlp(float* __restrict__ S,
                                             const HT* __restrict__ h,
                                             const float* __restrict__ W1,
                                             const float* __restrict__ b1,
                                             const float* __restrict__ W2,
                                             const float* __restrict__ b2,
                                             float* __restrict__ gsum,
                                             float* __restrict__ gsq, int N) {
    __shared__ __align__(16) float W1s[NH * NH2];     // 32 KB
    __shared__ __align__(16) float Ts[32 * 68];       // 8.7 KB
    __shared__ __align__(16) float T2s[32 * 132];     // 16.9 KB
    __shared__ __align__(16) float b1s[NH2];
    __shared__ __align__(16) float b2s[NH];
    __shared__ float red[2 * 64 * 8];                 // 4 KB

    int t = threadIdx.x;
    {
        const float4* src = (const float4*)W1;
        float4* dst4 = (float4*)W1s;
#pragma unroll
        for (int i = 0; i < 8; ++i) dst4[t + 256 * i] = src[t + 256 * i];
        if (t < NH2) b1s[t] = b1[t];
        else if (t < NH2 + NH) b2s[t - NH2] = b2[t - NH2];
    }
    __syncthreads();

    int a = t & 7;
    int b = t >> 3;  // 0..31
    float2 s_sum = {0.f, 0.f}, s_sq = {0.f, 0.f};

    int ntiles = N / 32;  // 3125
    for (int tile = blockIdx.x; tile < ntiles; tile += gridDim.x) {
        // ---- stage T = h + S (32 nodes x 64) ----
        {
            int node = t >> 3;
            int cb = (t & 7) * 8;
            size_t base = (size_t)(tile * 32 + node) * NH + cb;
            float sv[8], hv[8];
            load8(S + base, sv);
            load8(h + base, hv);
#pragma unroll
            for (int j = 0; j < 8; ++j) Ts[node * 68 + cb + j] = sv[j] + hv[j];
        }
        __syncthreads();
        // ---- phase 1: T2 = relu(T@W1 + b1) ----
        {
            float4 acc0 = *(const float4*)&b1s[4 * b];
            float4 acc1 = acc0, acc2 = acc0, acc3 = acc0;
#pragma unroll 8
            for (int k = 0; k < NH; ++k) {
                float4 w = *(const float4*)&W1s[k * NH2 + 4 * b];
                float t0 = Ts[a * 68 + k];
                float t1 = Ts[(a + 8) * 68 + k];
                float t2 = Ts[(a + 16) * 68 + k];
                float t3 = Ts[(a + 24) * 68 + k];
                acc0.x += t0 * w.x; acc0.y += t0 * w.y; acc0.z += t0 * w.z; acc0.w += t0 * w.w;
                acc1.x += t1 * w.x; acc1.y += t1 * w.y; acc1.z += t1 * w.z; acc1.w += t1 * w.w;
                acc2.x += t2 * w.x; acc2.y += t2 * w.y; acc2.z += t2 * w.z; acc2.w += t2 * w.w;
                acc3.x += t3 * w.x; acc3.y += t3 * w.y; acc3.z += t3 * w.z; acc3.w += t3 * w.w;
            }
            float4 r;
            r.x = fmaxf(acc0.x, 0.f); r.y = fmaxf(acc0.y, 0.f); r.z = fmaxf(acc0.z, 0.f); r.w = fmaxf(acc0.w, 0.f);
            *(float4*)&T2s[a * 132 + 4 * b] = r;
            r.x = fmaxf(acc1.x, 0.f); r.y = fmaxf(acc1.y, 0.f); r.z = fmaxf(acc1.z, 0.f); r.w = fmaxf(acc1.w, 0.f);
            *(float4*)&T2s[(a + 8) * 132 + 4 * b] = r;
            r.x = fmaxf(acc2.x, 0.f); r.y = fmaxf(acc2.y, 0.f); r.z = fmaxf(acc2.z, 0.f); r.w = fmaxf(acc2.w, 0.f);
            *(float4*)&T2s[(a + 16) * 132 + 4 * b] = r;
            r.x = fmaxf(acc3.x, 0.f); r.y = fmaxf(acc3.y, 0.f); r.z = fmaxf(acc3.z, 0.f); r.w = fmaxf(acc3.w, 0.f);
            *(float4*)&T2s[(a + 24) * 132 + 4 * b] = r;
        }
        __syncthreads();
        // ---- phase 2: m = T2 @ W2 + b2 -> overwrite S; BN stats ----
        {
            float2 acc0, acc1, acc2, acc3;
            acc0.x = b2s[2 * b]; acc0.y = b2s[2 * b + 1];
            acc1 = acc0; acc2 = acc0; acc3 = acc0;
#pragma unroll 4
            for (int j = 0; j < NH2; ++j) {
                float2 w = *(const float2*)&W2[j * NH + 2 * b];
                float t0 = T2s[a * 132 + j];
                float t1 = T2s[(a + 8) * 132 + j];
                float t2 = T2s[(a + 16) * 132 + j];
                float t3 = T2s[(a + 24) * 132 + j];
                acc0.x += t0 * w.x; acc0.y += t0 * w.y;
                acc1.x += t1 * w.x; acc1.y += t1 * w.y;
                acc2.x += t2 * w.x; acc2.y += t2 * w.y;
                acc3.x += t3 * w.x; acc3.y += t3 * w.y;
            }
            int base = tile * 32;
            *(float2*)&S[(size_t)(base + a) * NH + 2 * b] = acc0;
            *(float2*)&S[(size_t)(base + a + 8) * NH + 2 * b] = acc1;
            *(float2*)&S[(size_t)(base + a + 16) * NH + 2 * b] = acc2;
            *(float2*)&S[(size_t)(base + a + 24) * NH + 2 * b] = acc3;
            s_sum.x += acc0.x + acc1.x + acc2.x + acc3.x;
            s_sum.y += acc0.y + acc1.y + acc2.y + acc3.y;
            s_sq.x += acc0.x * acc0.x + acc1.x * acc1.x + acc2.x * acc2.x + acc3.x * acc3.x;
            s_sq.y += acc0.y * acc0.y + acc1.y * acc1.y + acc2.y * acc2.y + acc3.y * acc3.y;
        }
        __syncthreads();
    }
    red[0 * 512 + (2 * b) * 8 + a] = s_sum.x;
    red[0 * 512 + (2 * b + 1) * 8 + a] = s_sum.y;
    red[1 * 512 + (2 * b) * 8 + a] = s_sq.x;
    red[1 * 512 + (2 * b + 1) * 8 + a] = s_sq.y;
    __syncthreads();
    if (t < 64) {
        float s = 0.f;
#pragma unroll
        for (int i = 0; i < 8; ++i) s += red[t * 8 + i];
        unsafeAtomicAdd(&gsum[t], s);
    } else if (t < 128) {
        int col = t - 64;
        float s = 0.f;
#pragma unroll
        for (int i = 0; i < 8; ++i) s += red[512 + col * 8 + i];
        unsafeAtomicAdd(&gsq[col], s);
    }
}

// ---------------------------------------------------------------------------
// BN finalize + ReLU + residual: h = relu((m-mean)*rstd*gamma + beta) + h
// m lives in S.
// ---------------------------------------------------------------------------
template <typename HT>
__global__ __launch_bounds__(256) void k_bn(const float* __restrict__ m,
                                            HT* __restrict__ h,
                                            const float* __restrict__ gsum,
                                            const float* __restrict__ gsq,
                                            const float* __restrict__ gamma,
                                            const float* __restrict__ beta, int N) {
    __shared__ float scale_s[NH], shift_s[NH];
    int t = threadIdx.x;
    if (t < NH) {
        float invN = 1.0f / (float)N;
        float mean = gsum[t] * invN;
        float var = gsq[t] * invN - mean * mean;
        float sc = gamma[t] * rsqrtf(var + BN_EPS);
        scale_s[t] = sc;
        shift_s[t] = beta[t] - mean * sc;
    }
    __syncthreads();
    int total = N * (NH / 8);  // groups of 8
    for (int i = blockIdx.x * 256 + t; i < total; i += gridDim.x * 256) {
        int cb = (i & 7) * 8;
        size_t base = (size_t)(i >> 3) * NH + cb;
        float mv[8], hv[8], r[8];
        load8(m + base, mv);
        load8(h + base, hv);
#pragma unroll
        for (int j = 0; j < 8; ++j)
            r[j] = fmaxf(mv[j] * scale_s[cb + j] + shift_s[cb + j], 0.f) + hv[j];
        store8(h + base, r);
    }
}

// ---------------------------------------------------------------------------
// Global add pool: g[batch[n]] += h[n]
// ---------------------------------------------------------------------------
template <typename HT>
__global__ __launch_bounds__(256) void k_pool(const HT* __restrict__ h,
                                              const int* __restrict__ batch,
                                              float* __restrict__ g, int N) {
    int gid = blockIdx.x * 256 + threadIdx.x;
    int node = gid >> 6;
    int lane = threadIdx.x & 63;
    if (node < N) {
        unsafeAtomicAdd(&g[(size_t)batch[node] * NH + lane], ldh(&h[(size_t)node * NH + lane]));
    }
}

// ---------------------------------------------------------------------------
// Readout: out = relu(g @ Wo1 + bo1) @ Wo2 + bo2. One wave per graph.
// ---------------------------------------------------------------------------
__global__ __launch_bounds__(256) void k_readout(const float* __restrict__ g,
                                                 const float* __restrict__ Wo1,
                                                 const float* __restrict__ bo1,
                                                 const float* __restrict__ Wo2,
                                                 const float* __restrict__ bo2,
                                                 float* __restrict__ out, int G) {
    int t = threadIdx.x;
    int lane = t & 63;
    int gi = blockIdx.x * 4 + (t >> 6);
    if (gi >= G) return;
    const float* gr = g + (size_t)gi * NH;
    float acc = bo1[lane];
#pragma unroll 8
    for (int j = 0; j < NH; ++j) acc += gr[j] * Wo1[j * NH + lane];
    float v = fmaxf(acc, 0.f) * Wo2[lane];
#pragma unroll
    for (int off = 32; off > 0; off >>= 1) v += __shfl_xor(v, off);
    if (lane == 0) out[gi] = v + bo2[0];
}

// ---------------------------------------------------------------------------
template <typename HT>
static void run_pipeline(void* const* d_in, float* S, HT* h, float* stats,
                         float* gpool, float* out, hipStream_t stream) {
    const float* x      = (const float*)d_in[0];
    const int*   ei     = (const int*)d_in[1];
    const int*   batch  = (const int*)d_in[3];
    const float* W_init = (const float*)d_in[4];
    const float* b_init = (const float*)d_in[5];
    const float* W1     = (const float*)d_in[6];
    const float* b1     = (const float*)d_in[7];
    const float* W2     = (const float*)d_in[8];
    const float* b2     = (const float*)d_in[9];
    const float* gamma  = (const float*)d_in[10];
    const float* beta   = (const float*)d_in[11];
    const float* Wo1    = (const float*)d_in[12];
    const float* bo1    = (const float*)d_in[13];
    const float* Wo2    = (const float*)d_in[14];
    const float* bo2    = (const float*)d_in[15];

    const size_t sbytes = (size_t)NN * NH * sizeof(float);

    k_proj<HT><<<2048, 256, 0, stream>>>(x, W_init, b_init, h, NN);

    for (int l = 0; l < NL; ++l) {
        hipMemsetAsync(S, 0, sbytes, stream);
        k_scatter<HT><<<(NE * 64) / 256, 256, 0, stream>>>(h, ei, S, NE);
        hipMemsetAsync(stats, 0, 128 * sizeof(float), stream);
        k_mlp<HT><<<1024, 256, 0, stream>>>(S, h,
                                            W1 + (size_t)l * NH * NH2, b1 + (size_t)l * NH2,
                                            W2 + (size_t)l * NH2 * NH, b2 + (size_t)l * NH,
                                            stats, stats + 64, NN);
        k_bn<HT><<<2048, 256, 0, stream>>>(S, h, stats, stats + 64,
                                           gamma + (size_t)l * NH, beta + (size_t)l * NH, NN);
    }

    hipMemsetAsync(gpool, 0, (size_t)NG * NH * sizeof(float), stream);
    k_pool<HT><<<(NN * 64) / 256, 256, 0, stream>>>(h, batch, gpool, NN);
    k_readout<<<NG / 4, 256, 0, stream>>>(gpool, Wo1, bo1, Wo2, bo2, out, NG);
}

extern "C" void kernel_launch(void* const* d_in, const int* in_sizes, int n_in,
                              void* d_out, int out_size, void* d_ws, size_t ws_size,
                              hipStream_t stream) {
    float* out = (float*)d_out;
    float* S = (float*)d_ws;  // N*64 fp32 (scatter acc, then m)
    const size_t nelem = (size_t)NN * NH;
    const size_t small = (128 + (size_t)NG * NH) * sizeof(float);

    // tier A (h fp32) needs 2 big fp32 buffers; tier B stores h as bf16.
    if (ws_size >= 2 * nelem * sizeof(float) + small) {
        float* h = S + nelem;
        float* stats = h + nelem;
        float* gpool = stats + 128;
        run_pipeline<float>(d_in, S, h, stats, gpool, out, stream);
    } else {
        bf16t* h = (bf16t*)(S + nelem);
        float* stats = (float*)((char*)h + nelem * sizeof(bf16t));
        float* gpool = stats + 128;
        run_pipeline<bf16t>(d_in, S, h, stats, gpool, out, stream);
    }
}

// Round 3
// 1300.635 us; speedup vs baseline: 1.5033x; 1.5033x over previous
//
#include <hip/hip_runtime.h>
#include <hip/hip_bf16.h>

#define NN 100000
#define NE 1600000
#define NF 32
#define NH 64
#define NH2 128
#define NL 4
#define NG 512
#define BN_EPS 1e-5f

typedef __hip_bfloat16 bf16t;

// ---- storage conversion helpers (h buffer is float or bf16) ----------------
__device__ inline unsigned int f2bfbits(float f) {
    unsigned int x = __float_as_uint(f);
    return (x + 0x7fffu + ((x >> 16) & 1u)) >> 16;  // RNE
}
__device__ inline float ldh(const float* p) { return *p; }
__device__ inline float ldh(const bf16t* p) {
    return __uint_as_float(((unsigned int)*(const unsigned short*)p) << 16);
}
__device__ inline void sth(float* p, float v) { *p = v; }
__device__ inline void sth(bf16t* p, float v) {
    *(unsigned short*)p = (unsigned short)f2bfbits(v);
}
__device__ inline void load8(const float* p, float* o) {
    float4 a = *(const float4*)p, b = *(const float4*)(p + 4);
    o[0] = a.x; o[1] = a.y; o[2] = a.z; o[3] = a.w;
    o[4] = b.x; o[5] = b.y; o[6] = b.z; o[7] = b.w;
}
__device__ inline void load8(const bf16t* p, float* o) {
    uint4 u = *(const uint4*)p;
    o[0] = __uint_as_float(u.x << 16); o[1] = __uint_as_float(u.x & 0xffff0000u);
    o[2] = __uint_as_float(u.y << 16); o[3] = __uint_as_float(u.y & 0xffff0000u);
    o[4] = __uint_as_float(u.z << 16); o[5] = __uint_as_float(u.z & 0xffff0000u);
    o[6] = __uint_as_float(u.w << 16); o[7] = __uint_as_float(u.w & 0xffff0000u);
}
__device__ inline void store8(float* p, const float* v) {
    *(float4*)p = make_float4(v[0], v[1], v[2], v[3]);
    *(float4*)(p + 4) = make_float4(v[4], v[5], v[6], v[7]);
}
__device__ inline void store8(bf16t* p, const float* v) {
    uint4 u;
    u.x = f2bfbits(v[0]) | (f2bfbits(v[1]) << 16);
    u.y = f2bfbits(v[2]) | (f2bfbits(v[3]) << 16);
    u.z = f2bfbits(v[4]) | (f2bfbits(v[5]) << 16);
    u.w = f2bfbits(v[6]) | (f2bfbits(v[7]) << 16);
    *(uint4*)p = u;
}

// ---------------------------------------------------------------------------
// Initial projection: h = x @ W_init + b_init   [N,32]@[32,64]
// ---------------------------------------------------------------------------
template <typename HT>
__global__ __launch_bounds__(256) void k_proj(const float* __restrict__ x,
                                              const float* __restrict__ W,
                                              const float* __restrict__ bias,
                                              HT* __restrict__ h, int N) {
    __shared__ __align__(16) float Ws[NF * NH];
    __shared__ float bs[NH];
    int t = threadIdx.x;
    for (int i = t; i < NF * NH; i += 256) Ws[i] = W[i];
    if (t < NH) bs[t] = bias[t];
    __syncthreads();
    int c = t & 63, gi = t >> 6;
    for (int n = blockIdx.x * 4 + gi; n < N; n += gridDim.x * 4) {
        const float* xr = x + n * NF;
        float acc = bs[c];
#pragma unroll
        for (int k = 0; k < NF; ++k) acc += xr[k] * Ws[k * NH + c];
        sth(&h[(size_t)n * NH + c], acc);
    }
}

// ---------------------------------------------------------------------------
// CSR build: deg histogram -> scan -> fill (dst-sorted src list)
// ---------------------------------------------------------------------------
__global__ __launch_bounds__(256) void k_hist(const int* __restrict__ ei,
                                              int* __restrict__ deg, int E) {
    int e = blockIdx.x * 256 + threadIdx.x;
    if (e < E) atomicAdd(&deg[ei[E + e]], 1);
}

// single-block exclusive scan of deg[N] -> rowptr[N+1] and cursor[N]
__global__ __launch_bounds__(1024) void k_scan(const int* __restrict__ deg,
                                               int* __restrict__ rowptr,
                                               int* __restrict__ cursor, int N) {
    __shared__ int bs[1024];
    int t = threadIdx.x;
    int per = (N + 1023) / 1024;
    int start = t * per;
    int end = min(start + per, N);
    int s = 0;
    for (int i = start; i < end; ++i) s += deg[i];
    bs[t] = s;
    __syncthreads();
    for (int off = 1; off < 1024; off <<= 1) {
        int v = (t >= off) ? bs[t - off] : 0;
        __syncthreads();
        bs[t] += v;
        __syncthreads();
    }
    int prefix = (t == 0) ? 0 : bs[t - 1];
    for (int i = start; i < end; ++i) {
        int d = deg[i];
        rowptr[i] = prefix;
        cursor[i] = prefix;
        prefix += d;
    }
    if (t == 0) rowptr[N] = bs[1023];
}

__global__ __launch_bounds__(256) void k_fill(const int* __restrict__ ei,
                                              int* __restrict__ cursor,
                                              int* __restrict__ csr_src, int E) {
    int e = blockIdx.x * 256 + threadIdx.x;
    if (e < E) {
        int pos = atomicAdd(&cursor[ei[E + e]], 1);
        csr_src[pos] = ei[e];
    }
}

// ---------------------------------------------------------------------------
// Gather aggregation: T[n] = h[n] + sum_{e in in(n)} h[src(e)]  (no atomics)
// One wave per node, lane = channel; coalesced full-row loads.
// ---------------------------------------------------------------------------
template <typename HT>
__global__ __launch_bounds__(256) void k_gather(const HT* __restrict__ h,
                                                const int* __restrict__ rowptr,
                                                const int* __restrict__ csr,
                                                float* __restrict__ T, int N) {
    int node = blockIdx.x * 4 + (threadIdx.x >> 6);
    int lane = threadIdx.x & 63;
    if (node >= N) return;
    int s = rowptr[node], e = rowptr[node + 1];
    float acc = ldh(&h[(size_t)node * NH + lane]);  // (1+eps)*h self term, eps=0
    int i = s;
    for (; i + 4 <= e; i += 4) {
        int s0 = csr[i], s1 = csr[i + 1], s2 = csr[i + 2], s3 = csr[i + 3];
        float a0 = ldh(&h[(size_t)s0 * NH + lane]);
        float a1 = ldh(&h[(size_t)s1 * NH + lane]);
        float a2 = ldh(&h[(size_t)s2 * NH + lane]);
        float a3 = ldh(&h[(size_t)s3 * NH + lane]);
        acc += (a0 + a1) + (a2 + a3);
    }
    for (; i < e; ++i) acc += ldh(&h[(size_t)csr[i] * NH + lane]);
    T[(size_t)node * NH + lane] = acc;
}

// ---------------------------------------------------------------------------
// Fallback (tier C): atomic scatter into pre-zeroed S, then S += h done in mlp?
// Kept identical to round-2 semantics: S[dst] += h[src]; mlp adds h.
// ---------------------------------------------------------------------------
template <typename HT>
__global__ __launch_bounds__(256) void k_scatter(const HT* __restrict__ h,
                                                 const int* __restrict__ ei,
                                                 float* __restrict__ S, int E) {
    int gid = blockIdx.x * 256 + threadIdx.x;
    int e = gid >> 6;
    int lane = threadIdx.x & 63;
    if (e < E) {
        int src = ei[e];
        int dst = ei[E + e];
        unsafeAtomicAdd(&S[(size_t)dst * NH + lane], ldh(&h[(size_t)src * NH + lane]));
    }
}
template <typename HT>
__global__ __launch_bounds__(256) void k_addself(const HT* __restrict__ h,
                                                 float* __restrict__ S, int N) {
    int i = blockIdx.x * 256 + threadIdx.x;
    int total = N * NH;
    for (; i < total; i += gridDim.x * 256) S[i] += ldh(&h[i]);
}

// ---------------------------------------------------------------------------
// MLP: S <- relu(S @ W1 + b1) @ W2 + b2  (S holds T=h+agg on entry, m on exit)
// Block-local alias: each 32-node tile fully staged to LDS before overwrite.
// Also accumulates BN partial sums (sum, sum^2) via block reduce + atomics.
// ---------------------------------------------------------------------------
__global__ __launch_bounds__(256) void k_mlp(float* __restrict__ S,
                                             const float* __restrict__ W1,
                                             const float* __restrict__ b1,
                                             const float* __restrict__ W2,
                                             const float* __restrict__ b2,
                                             float* __restrict__ gsum,
                                             float* __restrict__ gsq, int N) {
    __shared__ __align__(16) float W1s[NH * NH2];     // 32 KB
    __shared__ __align__(16) float Ts[32 * 68];       // 8.7 KB
    __shared__ __align__(16) float T2s[32 * 132];     // 16.9 KB
    __shared__ __align__(16) float b1s[NH2];
    __shared__ __align__(16) float b2s[NH];
    __shared__ float red[2 * 64 * 8];                 // 4 KB

    int t = threadIdx.x;
    {
        const float4* src = (const float4*)W1;
        float4* dst4 = (float4*)W1s;
#pragma unroll
        for (int i = 0; i < 8; ++i) dst4[t + 256 * i] = src[t + 256 * i];
        if (t < NH2) b1s[t] = b1[t];
        else if (t < NH2 + NH) b2s[t - NH2] = b2[t - NH2];
    }
    __syncthreads();

    int a = t & 7;
    int b = t >> 3;  // 0..31
    float2 s_sum = {0.f, 0.f}, s_sq = {0.f, 0.f};

    int ntiles = N / 32;  // 3125
    for (int tile = blockIdx.x; tile < ntiles; tile += gridDim.x) {
        // ---- stage T tile (32 nodes x 64) ----
        {
            int node = t >> 3;
            int cb = (t & 7) * 8;
            size_t base = (size_t)(tile * 32 + node) * NH + cb;
            float sv[8];
            load8(S + base, sv);
#pragma unroll
            for (int j = 0; j < 8; ++j) Ts[node * 68 + cb + j] = sv[j];
        }
        __syncthreads();
        // ---- phase 1: T2 = relu(T@W1 + b1) ----
        {
            float4 acc0 = *(const float4*)&b1s[4 * b];
            float4 acc1 = acc0, acc2 = acc0, acc3 = acc0;
#pragma unroll 8
            for (int k = 0; k < NH; ++k) {
                float4 w = *(const float4*)&W1s[k * NH2 + 4 * b];
                float t0 = Ts[a * 68 + k];
                float t1 = Ts[(a + 8) * 68 + k];
                float t2 = Ts[(a + 16) * 68 + k];
                float t3 = Ts[(a + 24) * 68 + k];
                acc0.x += t0 * w.x; acc0.y += t0 * w.y; acc0.z += t0 * w.z; acc0.w += t0 * w.w;
                acc1.x += t1 * w.x; acc1.y += t1 * w.y; acc1.z += t1 * w.z; acc1.w += t1 * w.w;
                acc2.x += t2 * w.x; acc2.y += t2 * w.y; acc2.z += t2 * w.z; acc2.w += t2 * w.w;
                acc3.x += t3 * w.x; acc3.y += t3 * w.y; acc3.z += t3 * w.z; acc3.w += t3 * w.w;
            }
            float4 r;
            r.x = fmaxf(acc0.x, 0.f); r.y = fmaxf(acc0.y, 0.f); r.z = fmaxf(acc0.z, 0.f); r.w = fmaxf(acc0.w, 0.f);
            *(float4*)&T2s[a * 132 + 4 * b] = r;
            r.x = fmaxf(acc1.x, 0.f); r.y = fmaxf(acc1.y, 0.f); r.z = fmaxf(acc1.z, 0.f); r.w = fmaxf(acc1.w, 0.f);
            *(float4*)&T2s[(a + 8) * 132 + 4 * b] = r;
            r.x = fmaxf(acc2.x, 0.f); r.y = fmaxf(acc2.y, 0.f); r.z = fmaxf(acc2.z, 0.f); r.w = fmaxf(acc2.w, 0.f);
            *(float4*)&T2s[(a + 16) * 132 + 4 * b] = r;
            r.x = fmaxf(acc3.x, 0.f); r.y = fmaxf(acc3.y, 0.f); r.z = fmaxf(acc3.z, 0.f); r.w = fmaxf(acc3.w, 0.f);
            *(float4*)&T2s[(a + 24) * 132 + 4 * b] = r;
        }
        __syncthreads();
        // ---- phase 2: m = T2 @ W2 + b2 -> overwrite S; BN stats ----
        {
            float2 acc0, acc1, acc2, acc3;
            acc0.x = b2s[2 * b]; acc0.y = b2s[2 * b + 1];
            acc1 = acc0; acc2 = acc0; acc3 = acc0;
#pragma unroll 4
            for (int j = 0; j < NH2; ++j) {
                float2 w = *(const float2*)&W2[j * NH + 2 * b];
                float t0 = T2s[a * 132 + j];
                float t1 = T2s[(a + 8) * 132 + j];
                float t2 = T2s[(a + 16) * 132 + j];
                float t3 = T2s[(a + 24) * 132 + j];
                acc0.x += t0 * w.x; acc0.y += t0 * w.y;
                acc1.x += t1 * w.x; acc1.y += t1 * w.y;
                acc2.x += t2 * w.x; acc2.y += t2 * w.y;
                acc3.x += t3 * w.x; acc3.y += t3 * w.y;
            }
            int base = tile * 32;
            *(float2*)&S[(size_t)(base + a) * NH + 2 * b] = acc0;
            *(float2*)&S[(size_t)(base + a + 8) * NH + 2 * b] = acc1;
            *(float2*)&S[(size_t)(base + a + 16) * NH + 2 * b] = acc2;
            *(float2*)&S[(size_t)(base + a + 24) * NH + 2 * b] = acc3;
            s_sum.x += acc0.x + acc1.x + acc2.x + acc3.x;
            s_sum.y += acc0.y + acc1.y + acc2.y + acc3.y;
            s_sq.x += acc0.x * acc0.x + acc1.x * acc1.x + acc2.x * acc2.x + acc3.x * acc3.x;
            s_sq.y += acc0.y * acc0.y + acc1.y * acc1.y + acc2.y * acc2.y + acc3.y * acc3.y;
        }
        __syncthreads();
    }
    red[0 * 512 + (2 * b) * 8 + a] = s_sum.x;
    red[0 * 512 + (2 * b + 1) * 8 + a] = s_sum.y;
    red[1 * 512 + (2 * b) * 8 + a] = s_sq.x;
    red[1 * 512 + (2 * b + 1) * 8 + a] = s_sq.y;
    __syncthreads();
    if (t < 64) {
        float s = 0.f;
#pragma unroll
        for (int i = 0; i < 8; ++i) s += red[t * 8 + i];
        unsafeAtomicAdd(&gsum[t], s);
    } else if (t < 128) {
        int col = t - 64;
        float s = 0.f;
#pragma unroll
        for (int i = 0; i < 8; ++i) s += red[512 + col * 8 + i];
        unsafeAtomicAdd(&gsq[col], s);
    }
}

// ---------------------------------------------------------------------------
// BN finalize + ReLU + residual: h = relu((m-mean)*rstd*gamma + beta) + h
// ---------------------------------------------------------------------------
template <typename HT>
__global__ __launch_bounds__(256) void k_bn(const float* __restrict__ m,
                                            HT* __restrict__ h,
                                            const float* __restrict__ gsum,
                                            const float* __restrict__ gsq,
                                            const float* __restrict__ gamma,
                                            const float* __restrict__ beta, int N) {
    __shared__ float scale_s[NH], shift_s[NH];
    int t = threadIdx.x;
    if (t < NH) {
        float invN = 1.0f / (float)N;
        float mean = gsum[t] * invN;
        float var = gsq[t] * invN - mean * mean;
        float sc = gamma[t] * rsqrtf(var + BN_EPS);
        scale_s[t] = sc;
        shift_s[t] = beta[t] - mean * sc;
    }
    __syncthreads();
    int total = N * (NH / 8);
    for (int i = blockIdx.x * 256 + t; i < total; i += gridDim.x * 256) {
        int cb = (i & 7) * 8;
        size_t base = (size_t)(i >> 3) * NH + cb;
        float mv[8], hv[8], r[8];
        load8(m + base, mv);
        load8(h + base, hv);
#pragma unroll
        for (int j = 0; j < 8; ++j)
            r[j] = fmaxf(mv[j] * scale_s[cb + j] + shift_s[cb + j], 0.f) + hv[j];
        store8(h + base, r);
    }
}

// ---------------------------------------------------------------------------
// Global add pool + readout
// ---------------------------------------------------------------------------
template <typename HT>
__global__ __launch_bounds__(256) void k_pool(const HT* __restrict__ h,
                                              const int* __restrict__ batch,
                                              float* __restrict__ g, int N) {
    int gid = blockIdx.x * 256 + threadIdx.x;
    int node = gid >> 6;
    int lane = threadIdx.x & 63;
    if (node < N) {
        unsafeAtomicAdd(&g[(size_t)batch[node] * NH + lane], ldh(&h[(size_t)node * NH + lane]));
    }
}

__global__ __launch_bounds__(256) void k_readout(const float* __restrict__ g,
                                                 const float* __restrict__ Wo1,
                                                 const float* __restrict__ bo1,
                                                 const float* __restrict__ Wo2,
                                                 const float* __restrict__ bo2,
                                                 float* __restrict__ out, int G) {
    int t = threadIdx.x;
    int lane = t & 63;
    int gi = blockIdx.x * 4 + (t >> 6);
    if (gi >= G) return;
    const float* gr = g + (size_t)gi * NH;
    float acc = bo1[lane];
#pragma unroll 8
    for (int j = 0; j < NH; ++j) acc += gr[j] * Wo1[j * NH + lane];
    float v = fmaxf(acc, 0.f) * Wo2[lane];
#pragma unroll
    for (int off = 32; off > 0; off >>= 1) v += __shfl_xor(v, off);
    if (lane == 0) out[gi] = v + bo2[0];
}

// ---------------------------------------------------------------------------
template <typename HT, bool USE_CSR>
static void run_pipeline(void* const* d_in, float* S, HT* h, int* csr_src,
                         int* rowptr, int* deg, int* cursor, float* stats,
                         float* gpool, float* out, hipStream_t stream) {
    const float* x      = (const float*)d_in[0];
    const int*   ei     = (const int*)d_in[1];
    const int*   batch  = (const int*)d_in[3];
    const float* W_init = (const float*)d_in[4];
    const float* b_init = (const float*)d_in[5];
    const float* W1     = (const float*)d_in[6];
    const float* b1     = (const float*)d_in[7];
    const float* W2     = (const float*)d_in[8];
    const float* b2     = (const float*)d_in[9];
    const float* gamma  = (const float*)d_in[10];
    const float* beta   = (const float*)d_in[11];
    const float* Wo1    = (const float*)d_in[12];
    const float* bo1    = (const float*)d_in[13];
    const float* Wo2    = (const float*)d_in[14];
    const float* bo2    = (const float*)d_in[15];

    if (USE_CSR) {
        hipMemsetAsync(deg, 0, NN * sizeof(int), stream);
        k_hist<<<(NE + 255) / 256, 256, 0, stream>>>(ei, deg, NE);
        k_scan<<<1, 1024, 0, stream>>>(deg, rowptr, cursor, NN);
        k_fill<<<(NE + 255) / 256, 256, 0, stream>>>(ei, cursor, csr_src, NE);
    }

    k_proj<HT><<<2048, 256, 0, stream>>>(x, W_init, b_init, h, NN);

    for (int l = 0; l < NL; ++l) {
        if (USE_CSR) {
            k_gather<HT><<<(NN + 3) / 4, 256, 0, stream>>>(h, rowptr, csr_src, S, NN);
        } else {
            hipMemsetAsync(S, 0, (size_t)NN * NH * sizeof(float), stream);
            k_scatter<HT><<<(NE * 64) / 256, 256, 0, stream>>>(h, ei, S, NE);
            k_addself<HT><<<2048, 256, 0, stream>>>(h, S, NN);
        }
        hipMemsetAsync(stats, 0, 128 * sizeof(float), stream);
        k_mlp<<<1024, 256, 0, stream>>>(S,
                                        W1 + (size_t)l * NH * NH2, b1 + (size_t)l * NH2,
                                        W2 + (size_t)l * NH2 * NH, b2 + (size_t)l * NH,
                                        stats, stats + 64, NN);
        k_bn<HT><<<2048, 256, 0, stream>>>(S, h, stats, stats + 64,
                                           gamma + (size_t)l * NH, beta + (size_t)l * NH, NN);
    }

    hipMemsetAsync(gpool, 0, (size_t)NG * NH * sizeof(float), stream);
    k_pool<HT><<<(NN * 64) / 256, 256, 0, stream>>>(h, batch, gpool, NN);
    k_readout<<<NG / 4, 256, 0, stream>>>(gpool, Wo1, bo1, Wo2, bo2, out, NG);
}

extern "C" void kernel_launch(void* const* d_in, const int* in_sizes, int n_in,
                              void* d_out, int out_size, void* d_ws, size_t ws_size,
                              hipStream_t stream) {
    float* out = (float*)d_out;
    const size_t nelem = (size_t)NN * NH;
    // aux: csr_src NE ints, rowptr NN+1, deg NN, cursor NN, stats 128 f, gpool NG*NH f
    const size_t aux = (size_t)NE * 4 + ((size_t)NN + 1) * 4 + (size_t)NN * 4 +
                       (size_t)NN * 4 + 128 * 4 + (size_t)NG * NH * 4 + 64;

    char* p = (char*)d_ws;
    float* S = (float*)p; p += nelem * sizeof(float);

    if (ws_size >= nelem * 4 + nelem * 4 + aux) {
        // tier A: fp32 h + CSR gather
        float* h = (float*)p; p += nelem * sizeof(float);
        int* csr_src = (int*)p; p += (size_t)NE * 4;
        int* rowptr = (int*)p; p += ((size_t)NN + 1) * 4;
        int* deg = (int*)p; p += (size_t)NN * 4;
        int* cursor = (int*)p; p += (size_t)NN * 4;
        float* stats = (float*)p; p += 128 * 4;
        float* gpool = (float*)p;
        run_pipeline<float, true>(d_in, S, h, csr_src, rowptr, deg, cursor,
                                  stats, gpool, out, stream);
    } else if (ws_size >= nelem * 4 + nelem * 2 + aux) {
        // tier B: bf16 h + CSR gather
        bf16t* h = (bf16t*)p; p += nelem * sizeof(bf16t);
        int* csr_src = (int*)p; p += (size_t)NE * 4;
        int* rowptr = (int*)p; p += ((size_t)NN + 1) * 4;
        int* deg = (int*)p; p += (size_t)NN * 4;
        int* cursor = (int*)p; p += (size_t)NN * 4;
        float* stats = (float*)p; p += 128 * 4;
        float* gpool = (float*)p;
        run_pipeline<bf16t, true>(d_in, S, h, csr_src, rowptr, deg, cursor,
                                  stats, gpool, out, stream);
    } else {
        // tier C: bf16 h + atomic scatter (minimal footprint)
        bf16t* h = (bf16t*)p; p += nelem * sizeof(bf16t);
        float* stats = (float*)p; p += 128 * 4;
        float* gpool = (float*)p;
        run_pipeline<bf16t, false>(d_in, S, h, nullptr, nullptr, nullptr, nullptr,
                                   stats, gpool, out, stream);
    }
}

// Round 8
// 1007.939 us; speedup vs baseline: 1.9398x; 1.2904x over previous
//
#include <hip/hip_runtime.h>
#include <hip/hip_bf16.h>

#define NN 100000
#define NE 1600000
#define NF 32
#define NH 64
#define NH2 128
#define NL 4
#define NG 512
#define BN_EPS 1e-5f
#define SCAN_CHUNK 1024

typedef __hip_bfloat16 bf16t;

// ---- storage conversion helpers ----------------
__device__ inline unsigned int f2bfbits(float f) {
    unsigned int x = __float_as_uint(f);
    return (x + 0x7fffu + ((x >> 16) & 1u)) >> 16;  // RNE
}
__device__ inline float ldh(const float* p) { return *p; }
__device__ inline float ldh(const bf16t* p) {
    return __uint_as_float(((unsigned int)*(const unsigned short*)p) << 16);
}
__device__ inline void sth(float* p, float v) { *p = v; }
__device__ inline void sth(bf16t* p, float v) {
    *(unsigned short*)p = (unsigned short)f2bfbits(v);
}
__device__ inline void load8(const float* p, float* o) {
    float4 a = *(const float4*)p, b = *(const float4*)(p + 4);
    o[0] = a.x; o[1] = a.y; o[2] = a.z; o[3] = a.w;
    o[4] = b.x; o[5] = b.y; o[6] = b.z; o[7] = b.w;
}
__device__ inline void load8(const bf16t* p, float* o) {
    uint4 u = *(const uint4*)p;
    o[0] = __uint_as_float(u.x << 16); o[1] = __uint_as_float(u.x & 0xffff0000u);
    o[2] = __uint_as_float(u.y << 16); o[3] = __uint_as_float(u.y & 0xffff0000u);
    o[4] = __uint_as_float(u.z << 16); o[5] = __uint_as_float(u.z & 0xffff0000u);
    o[6] = __uint_as_float(u.w << 16); o[7] = __uint_as_float(u.w & 0xffff0000u);
}
__device__ inline void store8(float* p, const float* v) {
    *(float4*)p = make_float4(v[0], v[1], v[2], v[3]);
    *(float4*)(p + 4) = make_float4(v[4], v[5], v[6], v[7]);
}
__device__ inline void store8(bf16t* p, const float* v) {
    uint4 u;
    u.x = f2bfbits(v[0]) | (f2bfbits(v[1]) << 16);
    u.y = f2bfbits(v[2]) | (f2bfbits(v[3]) << 16);
    u.z = f2bfbits(v[4]) | (f2bfbits(v[5]) << 16);
    u.w = f2bfbits(v[6]) | (f2bfbits(v[7]) << 16);
    *(uint4*)p = u;
}

// ---------------------------------------------------------------------------
// Initial projection: h = x @ W_init + b_init   [N,32]@[32,64]
// Optionally also writes bf16 shadow copy hb (gather read path).
// ---------------------------------------------------------------------------
template <typename HT, bool HB>
__global__ __launch_bounds__(256) void k_proj(const float* __restrict__ x,
                                              const float* __restrict__ W,
                                              const float* __restrict__ bias,
                                              HT* __restrict__ h,
                                              bf16t* __restrict__ hb, int N) {
    __shared__ __align__(16) float Ws[NF * NH];
    __shared__ float bs[NH];
    int t = threadIdx.x;
    for (int i = t; i < NF * NH; i += 256) Ws[i] = W[i];
    if (t < NH) bs[t] = bias[t];
    __syncthreads();
    int c = t & 63, gi = t >> 6;
    for (int n = blockIdx.x * 4 + gi; n < N; n += gridDim.x * 4) {
        const float* xr = x + n * NF;
        float acc = bs[c];
#pragma unroll
        for (int k = 0; k < NF; ++k) acc += xr[k] * Ws[k * NH + c];
        sth(&h[(size_t)n * NH + c], acc);
        if constexpr (HB) sth(&hb[(size_t)n * NH + c], acc);
    }
}

// ---------------------------------------------------------------------------
// CSR build: histogram -> 3-pass parallel scan -> fill
// ---------------------------------------------------------------------------
__global__ __launch_bounds__(256) void k_hist(const int* __restrict__ ei,
                                              int* __restrict__ deg, int E) {
    int e = blockIdx.x * 256 + threadIdx.x;
    if (e < E) atomicAdd(&deg[ei[E + e]], 1);
}

__global__ __launch_bounds__(256) void k_blocksum(const int* __restrict__ deg,
                                                  int* __restrict__ partials, int N) {
    __shared__ int red[256];
    int t = threadIdx.x;
    int base = blockIdx.x * SCAN_CHUNK + t * 4;
    int s = 0;
    if (base + 3 < N) {
        int4 v = *(const int4*)&deg[base];
        s = v.x + v.y + v.z + v.w;
    } else {
        for (int i = 0; i < 4; ++i) if (base + i < N) s += deg[base + i];
    }
    red[t] = s;
    __syncthreads();
    for (int off = 128; off > 0; off >>= 1) {
        if (t < off) red[t] += red[t + off];
        __syncthreads();
    }
    if (t == 0) partials[blockIdx.x] = red[0];
}

__global__ __launch_bounds__(128) void k_scanpartials(int* __restrict__ partials, int nb) {
    __shared__ int bs[128];
    int t = threadIdx.x;
    int v = (t < nb) ? partials[t] : 0;
    bs[t] = v;
    __syncthreads();
    for (int off = 1; off < 128; off <<= 1) {
        int u = (t >= off) ? bs[t - off] : 0;
        __syncthreads();
        bs[t] += u;
        __syncthreads();
    }
    if (t < nb) partials[t] = bs[t] - v;  // exclusive
}

__global__ __launch_bounds__(256) void k_scanfinal(const int* __restrict__ deg,
                                                   const int* __restrict__ partials,
                                                   int* __restrict__ rowptr,
                                                   int* __restrict__ cursor, int N, int E) {
    __shared__ int red[256];
    int t = threadIdx.x;
    int base = blockIdx.x * SCAN_CHUNK + t * 4;
    int v0 = 0, v1 = 0, v2 = 0, v3 = 0;
    if (base + 3 < N) {
        int4 v = *(const int4*)&deg[base];
        v0 = v.x; v1 = v.y; v2 = v.z; v3 = v.w;
    } else {
        if (base < N) v0 = deg[base];
        if (base + 1 < N) v1 = deg[base + 1];
        if (base + 2 < N) v2 = deg[base + 2];
        if (base + 3 < N) v3 = deg[base + 3];
    }
    int s = v0 + v1 + v2 + v3;
    red[t] = s;
    __syncthreads();
    for (int off = 1; off < 256; off <<= 1) {
        int u = (t >= off) ? red[t - off] : 0;
        __syncthreads();
        red[t] += u;
        __syncthreads();
    }
    int pre = partials[blockIdx.x] + red[t] - s;
    int p0 = pre, p1 = pre + v0, p2 = p1 + v1, p3 = p2 + v2;
    if (base + 3 < N) {
        *(int4*)&rowptr[base] = make_int4(p0, p1, p2, p3);
        *(int4*)&cursor[base] = make_int4(p0, p1, p2, p3);
    } else {
        if (base < N) { rowptr[base] = p0; cursor[base] = p0; }
        if (base + 1 < N) { rowptr[base + 1] = p1; cursor[base + 1] = p1; }
        if (base + 2 < N) { rowptr[base + 2] = p2; cursor[base + 2] = p2; }
        if (base + 3 < N) { rowptr[base + 3] = p3; cursor[base + 3] = p3; }
    }
    if (blockIdx.x == 0 && t == 0) rowptr[N] = E;
}

__global__ __launch_bounds__(256) void k_fill(const int* __restrict__ ei,
                                              int* __restrict__ cursor,
                                              int* __restrict__ csr_src, int E) {
    int e = blockIdx.x * 256 + threadIdx.x;
    if (e < E) {
        int pos = atomicAdd(&cursor[ei[E + e]], 1);
        csr_src[pos] = ei[e];
    }
}

// ---------------------------------------------------------------------------
// Gather aggregation: T[n] = hself[n] + sum_{e in in(n)} hnb[src(e)]
// ---------------------------------------------------------------------------
template <typename HS, typename HN>
__global__ __launch_bounds__(256) void k_gather(const HS* __restrict__ hself,
                                                const HN* __restrict__ hnb,
                                                const int* __restrict__ rowptr,
                                                const int* __restrict__ csr,
                                                float* __restrict__ T, int N) {
    int node = blockIdx.x * 4 + (threadIdx.x >> 6);
    int lane = threadIdx.x & 63;
    if (node >= N) return;
    int s = rowptr[node], e = rowptr[node + 1];
    float acc = ldh(&hself[(size_t)node * NH + lane]);  // self term (eps=0)
    int i = s;
    for (; i + 4 <= e; i += 4) {
        int s0 = csr[i], s1 = csr[i + 1], s2 = csr[i + 2], s3 = csr[i + 3];
        float a0 = ldh(&hnb[(size_t)s0 * NH + lane]);
        float a1 = ldh(&hnb[(size_t)s1 * NH + lane]);
        float a2 = ldh(&hnb[(size_t)s2 * NH + lane]);
        float a3 = ldh(&hnb[(size_t)s3 * NH + lane]);
        acc += (a0 + a1) + (a2 + a3);
    }
    for (; i < e; ++i) acc += ldh(&hnb[(size_t)csr[i] * NH + lane]);
    T[(size_t)node * NH + lane] = acc;
}

// ---------------------------------------------------------------------------
// Fallback (tier C): atomic scatter path
// ---------------------------------------------------------------------------
template <typename HT>
__global__ __launch_bounds__(256) void k_scatter(const HT* __restrict__ h,
                                                 const int* __restrict__ ei,
                                                 float* __restrict__ S, int E) {
    int gid = blockIdx.x * 256 + threadIdx.x;
    int e = gid >> 6;
    int lane = threadIdx.x & 63;
    if (e < E) {
        int src = ei[e];
        int dst = ei[E + e];
        unsafeAtomicAdd(&S[(size_t)dst * NH + lane], ldh(&h[(size_t)src * NH + lane]));
    }
}
template <typename HT>
__global__ __launch_bounds__(256) void k_addself(const HT* __restrict__ h,
                                                 float* __restrict__ S, int N) {
    int i = blockIdx.x * 256 + threadIdx.x;
    int total = N * NH;
    for (; i < total; i += gridDim.x * 256) S[i] += ldh(&h[i]);
}

// ---------------------------------------------------------------------------
// MLP: S <- relu(S @ W1 + b1) @ W2 + b2  (in-place per 32-node tile via LDS)
// + BN partial sums.
// ---------------------------------------------------------------------------
__global__ __launch_bounds__(256) void k_mlp(float* __restrict__ S,
                                             const float* __restrict__ W1,
                                             const float* __restrict__ b1,
                                             const float* __restrict__ W2,
                                             const float* __restrict__ b2,
                                             float* __restrict__ gsum,
                                             float* __restrict__ gsq, int N) {
    __shared__ __align__(16) float W1s[NH * NH2];     // 32 KB
    __shared__ __align__(16) float Ts[32 * 68];       // 8.7 KB
    __shared__ __align__(16) float T2s[32 * 132];     // 16.9 KB
    __shared__ __align__(16) float b1s[NH2];
    __shared__ __align__(16) float b2s[NH];
    __shared__ float red[2 * 64 * 8];                 // 4 KB

    int t = threadIdx.x;
    {
        const float4* src = (const float4*)W1;
        float4* dst4 = (float4*)W1s;
#pragma unroll
        for (int i = 0; i < 8; ++i) dst4[t + 256 * i] = src[t + 256 * i];
        if (t < NH2) b1s[t] = b1[t];
        else if (t < NH2 + NH) b2s[t - NH2] = b2[t - NH2];
    }
    __syncthreads();

    int a = t & 7;
    int b = t >> 3;  // 0..31
    float2 s_sum = {0.f, 0.f}, s_sq = {0.f, 0.f};

    int ntiles = N / 32;  // 3125
    for (int tile = blockIdx.x; tile < ntiles; tile += gridDim.x) {
        {
            int node = t >> 3;
            int cb = (t & 7) * 8;
            size_t base = (size_t)(tile * 32 + node) * NH + cb;
            float sv[8];
            load8(S + base, sv);
#pragma unroll
            for (int j = 0; j < 8; ++j) Ts[node * 68 + cb + j] = sv[j];
        }
        __syncthreads();
        {
            float4 acc0 = *(const float4*)&b1s[4 * b];
            float4 acc1 = acc0, acc2 = acc0, acc3 = acc0;
#pragma unroll 8
            for (int k = 0; k < NH; ++k) {
                float4 w = *(const float4*)&W1s[k * NH2 + 4 * b];
                float t0 = Ts[a * 68 + k];
                float t1 = Ts[(a + 8) * 68 + k];
                float t2 = Ts[(a + 16) * 68 + k];
                float t3 = Ts[(a + 24) * 68 + k];
                acc0.x += t0 * w.x; acc0.y += t0 * w.y; acc0.z += t0 * w.z; acc0.w += t0 * w.w;
                acc1.x += t1 * w.x; acc1.y += t1 * w.y; acc1.z += t1 * w.z; acc1.w += t1 * w.w;
                acc2.x += t2 * w.x; acc2.y += t2 * w.y; acc2.z += t2 * w.z; acc2.w += t2 * w.w;
                acc3.x += t3 * w.x; acc3.y += t3 * w.y; acc3.z += t3 * w.z; acc3.w += t3 * w.w;
            }
            float4 r;
            r.x = fmaxf(acc0.x, 0.f); r.y = fmaxf(acc0.y, 0.f); r.z = fmaxf(acc0.z, 0.f); r.w = fmaxf(acc0.w, 0.f);
            *(float4*)&T2s[a * 132 + 4 * b] = r;
            r.x = fmaxf(acc1.x, 0.f); r.y = fmaxf(acc1.y, 0.f); r.z = fmaxf(acc1.z, 0.f); r.w = fmaxf(acc1.w, 0.f);
            *(float4*)&T2s[(a + 8) * 132 + 4 * b] = r;
            r.x = fmaxf(acc2.x, 0.f); r.y = fmaxf(acc2.y, 0.f); r.z = fmaxf(acc2.z, 0.f); r.w = fmaxf(acc2.w, 0.f);
            *(float4*)&T2s[(a + 16) * 132 + 4 * b] = r;
            r.x = fmaxf(acc3.x, 0.f); r.y = fmaxf(acc3.y, 0.f); r.z = fmaxf(acc3.z, 0.f); r.w = fmaxf(acc3.w, 0.f);
            *(float4*)&T2s[(a + 24) * 132 + 4 * b] = r;
        }
        __syncthreads();
        {
            float2 acc0, acc1, acc2, acc3;
            acc0.x = b2s[2 * b]; acc0.y = b2s[2 * b + 1];
            acc1 = acc0; acc2 = acc0; acc3 = acc0;
#pragma unroll 4
            for (int j = 0; j < NH2; ++j) {
                float2 w = *(const float2*)&W2[j * NH + 2 * b];
                float t0 = T2s[a * 132 + j];
                float t1 = T2s[(a + 8) * 132 + j];
                float t2 = T2s[(a + 16) * 132 + j];
                float t3 = T2s[(a + 24) * 132 + j];
                acc0.x += t0 * w.x; acc0.y += t0 * w.y;
                acc1.x += t1 * w.x; acc1.y += t1 * w.y;
                acc2.x += t2 * w.x; acc2.y += t2 * w.y;
                acc3.x += t3 * w.x; acc3.y += t3 * w.y;
            }
            int base = tile * 32;
            *(float2*)&S[(size_t)(base + a) * NH + 2 * b] = acc0;
            *(float2*)&S[(size_t)(base + a + 8) * NH + 2 * b] = acc1;
            *(float2*)&S[(size_t)(base + a + 16) * NH + 2 * b] = acc2;
            *(float2*)&S[(size_t)(base + a + 24) * NH + 2 * b] = acc3;
            s_sum.x += acc0.x + acc1.x + acc2.x + acc3.x;
            s_sum.y += acc0.y + acc1.y + acc2.y + acc3.y;
            s_sq.x += acc0.x * acc0.x + acc1.x * acc1.x + acc2.x * acc2.x + acc3.x * acc3.x;
            s_sq.y += acc0.y * acc0.y + acc1.y * acc1.y + acc2.y * acc2.y + acc3.y * acc3.y;
        }
        __syncthreads();
    }
    red[0 * 512 + (2 * b) * 8 + a] = s_sum.x;
    red[0 * 512 + (2 * b + 1) * 8 + a] = s_sum.y;
    red[1 * 512 + (2 * b) * 8 + a] = s_sq.x;
    red[1 * 512 + (2 * b + 1) * 8 + a] = s_sq.y;
    __syncthreads();
    if (t < 64) {
        float s = 0.f;
#pragma unroll
        for (int i = 0; i < 8; ++i) s += red[t * 8 + i];
        unsafeAtomicAdd(&gsum[t], s);
    } else if (t < 128) {
        int col = t - 64;
        float s = 0.f;
#pragma unroll
        for (int i = 0; i < 8; ++i) s += red[512 + col * 8 + i];
        unsafeAtomicAdd(&gsq[col], s);
    }
}

// ---------------------------------------------------------------------------
// BN finalize + ReLU + residual: h = relu((m-mean)*rstd*gamma + beta) + h
// Optionally refreshes bf16 shadow hb.
// ---------------------------------------------------------------------------
template <typename HT, bool HB>
__global__ __launch_bounds__(256) void k_bn(const float* __restrict__ m,
                                            HT* __restrict__ h,
                                            bf16t* __restrict__ hb,
                                            const float* __restrict__ gsum,
                                            const float* __restrict__ gsq,
                                            const float* __restrict__ gamma,
                                            const float* __restrict__ beta, int N) {
    __shared__ float scale_s[NH], shift_s[NH];
    int t = threadIdx.x;
    if (t < NH) {
        float invN = 1.0f / (float)N;
        float mean = gsum[t] * invN;
        float var = gsq[t] * invN - mean * mean;
        float sc = gamma[t] * rsqrtf(var + BN_EPS);
        scale_s[t] = sc;
        shift_s[t] = beta[t] - mean * sc;
    }
    __syncthreads();
    int total = N * (NH / 8);
    for (int i = blockIdx.x * 256 + t; i < total; i += gridDim.x * 256) {
        int cb = (i & 7) * 8;
        size_t base = (size_t)(i >> 3) * NH + cb;
        float mv[8], hv[8], r[8];
        load8(m + base, mv);
        load8(h + base, hv);
#pragma unroll
        for (int j = 0; j < 8; ++j)
            r[j] = fmaxf(mv[j] * scale_s[cb + j] + shift_s[cb + j], 0.f) + hv[j];
        store8(h + base, r);
        if constexpr (HB) store8(hb + base, r);
    }
}

// ---------------------------------------------------------------------------
// Global add pool + readout
// ---------------------------------------------------------------------------
template <typename HT>
__global__ __launch_bounds__(256) void k_pool(const HT* __restrict__ h,
                                              const int* __restrict__ batch,
                                              float* __restrict__ g, int N) {
    int gid = blockIdx.x * 256 + threadIdx.x;
    int node = gid >> 6;
    int lane = threadIdx.x & 63;
    if (node < N) {
        unsafeAtomicAdd(&g[(size_t)batch[node] * NH + lane], ldh(&h[(size_t)node * NH + lane]));
    }
}

__global__ __launch_bounds__(256) void k_readout(const float* __restrict__ g,
                                                 const float* __restrict__ Wo1,
                                                 const float* __restrict__ bo1,
                                                 const float* __restrict__ Wo2,
                                                 const float* __restrict__ bo2,
                                                 float* __restrict__ out, int G) {
    int t = threadIdx.x;
    int lane = t & 63;
    int gi = blockIdx.x * 4 + (t >> 6);
    if (gi >= G) return;
    const float* gr = g + (size_t)gi * NH;
    float acc = bo1[lane];
#pragma unroll 8
    for (int j = 0; j < NH; ++j) acc += gr[j] * Wo1[j * NH + lane];
    float v = fmaxf(acc, 0.f) * Wo2[lane];
#pragma unroll
    for (int off = 32; off > 0; off >>= 1) v += __shfl_xor(v, off);
    if (lane == 0) out[gi] = v + bo2[0];
}

// ---------------------------------------------------------------------------
template <typename HT, bool USE_CSR, bool HB>
static void run_pipeline(void* const* d_in, float* S, HT* h, bf16t* hb, int* csr_src,
                         int* rowptr, int* deg, int* cursor, int* partials,
                         float* stats, float* gpool, float* out, hipStream_t stream) {
    const float* x      = (const float*)d_in[0];
    const int*   ei     = (const int*)d_in[1];
    const int*   batch  = (const int*)d_in[3];
    const float* W_init = (const float*)d_in[4];
    const float* b_init = (const float*)d_in[5];
    const float* W1     = (const float*)d_in[6];
    const float* b1     = (const float*)d_in[7];
    const float* W2     = (const float*)d_in[8];
    const float* b2     = (const float*)d_in[9];
    const float* gamma  = (const float*)d_in[10];
    const float* beta   = (const float*)d_in[11];
    const float* Wo1    = (const float*)d_in[12];
    const float* bo1    = (const float*)d_in[13];
    const float* Wo2    = (const float*)d_in[14];
    const float* bo2    = (const float*)d_in[15];

    if (USE_CSR) {
        const int nb = (NN + SCAN_CHUNK - 1) / SCAN_CHUNK;  // 98
        hipMemsetAsync(deg, 0, NN * sizeof(int), stream);
        k_hist<<<(NE + 255) / 256, 256, 0, stream>>>(ei, deg, NE);
        k_blocksum<<<nb, 256, 0, stream>>>(deg, partials, NN);
        k_scanpartials<<<1, 128, 0, stream>>>(partials, nb);
        k_scanfinal<<<nb, 256, 0, stream>>>(deg, partials, rowptr, cursor, NN, NE);
        k_fill<<<(NE + 255) / 256, 256, 0, stream>>>(ei, cursor, csr_src, NE);
    }

    k_proj<HT, HB><<<2048, 256, 0, stream>>>(x, W_init, b_init, h, hb, NN);

    for (int l = 0; l < NL; ++l) {
        if (USE_CSR) {
            if constexpr (HB) {
                k_gather<HT, bf16t><<<(NN + 3) / 4, 256, 0, stream>>>(h, hb, rowptr, csr_src, S, NN);
            } else {
                k_gather<HT, HT><<<(NN + 3) / 4, 256, 0, stream>>>(h, h, rowptr, csr_src, S, NN);
            }
        } else {
            hipMemsetAsync(S, 0, (size_t)NN * NH * sizeof(float), stream);
            k_scatter<HT><<<(NE * 64) / 256, 256, 0, stream>>>(h, ei, S, NE);
            k_addself<HT><<<2048, 256, 0, stream>>>(h, S, NN);
        }
        hipMemsetAsync(stats, 0, 128 * sizeof(float), stream);
        k_mlp<<<1024, 256, 0, stream>>>(S,
                                        W1 + (size_t)l * NH * NH2, b1 + (size_t)l * NH2,
                                        W2 + (size_t)l * NH2 * NH, b2 + (size_t)l * NH,
                                        stats, stats + 64, NN);
        k_bn<HT, HB><<<2048, 256, 0, stream>>>(S, h, hb, stats, stats + 64,
                                               gamma + (size_t)l * NH, beta + (size_t)l * NH, NN);
    }

    hipMemsetAsync(gpool, 0, (size_t)NG * NH * sizeof(float), stream);
    k_pool<HT><<<(NN * 64) / 256, 256, 0, stream>>>(h, batch, gpool, NN);
    k_readout<<<NG / 4, 256, 0, stream>>>(gpool, Wo1, bo1, Wo2, bo2, out, NG);
}

static inline size_t align256(size_t x) { return (x + 255) & ~(size_t)255; }

extern "C" void kernel_launch(void* const* d_in, const int* in_sizes, int n_in,
                              void* d_out, int out_size, void* d_ws, size_t ws_size,
                              hipStream_t stream) {
    float* out = (float*)d_out;
    const size_t nelem = (size_t)NN * NH;
    const size_t sz_S = align256(nelem * 4);
    const size_t sz_hf = align256(nelem * 4);
    const size_t sz_hb = align256(nelem * 2);   // bf16 buffer (shadow or h)
    const size_t sz_csr = align256((size_t)NE * 4);
    const size_t sz_row = align256(((size_t)NN + 4) * 4);
    const size_t sz_deg = align256((size_t)NN * 4);
    const size_t sz_cur = align256((size_t)NN * 4);
    const size_t sz_par = align256(256 * 4);
    const size_t sz_sta = align256(128 * 4);
    const size_t sz_gpl = align256((size_t)NG * NH * 4);
    const size_t aux = sz_csr + sz_row + sz_deg + sz_cur + sz_par + sz_sta + sz_gpl;

    char* p = (char*)d_ws;
    float* S = (float*)p; p += sz_S;

    if (ws_size >= sz_S + sz_hf + sz_hb + aux) {
        // tier A2: fp32 h + bf16 shadow for gather reads
        float* h = (float*)p; p += sz_hf;
        bf16t* hb = (bf16t*)p; p += sz_hb;
        int* csr_src = (int*)p; p += sz_csr;
        int* rowptr = (int*)p; p += sz_row;
        int* deg = (int*)p; p += sz_deg;
        int* cursor = (int*)p; p += sz_cur;
        int* partials = (int*)p; p += sz_par;
        float* stats = (float*)p; p += sz_sta;
        float* gpool = (float*)p;
        run_pipeline<float, true, true>(d_in, S, h, hb, csr_src, rowptr, deg, cursor,
                                        partials, stats, gpool, out, stream);
    } else if (ws_size >= sz_S + sz_hf + aux) {
        // tier A: fp32 h, gather reads fp32 (round-3 behavior)
        float* h = (float*)p; p += sz_hf;
        int* csr_src = (int*)p; p += sz_csr;
        int* rowptr = (int*)p; p += sz_row;
        int* deg = (int*)p; p += sz_deg;
        int* cursor = (int*)p; p += sz_cur;
        int* partials = (int*)p; p += sz_par;
        float* stats = (float*)p; p += sz_sta;
        float* gpool = (float*)p;
        run_pipeline<float, true, false>(d_in, S, h, nullptr, csr_src, rowptr, deg, cursor,
                                         partials, stats, gpool, out, stream);
    } else if (ws_size >= sz_S + sz_hb + aux) {
        // tier B: bf16 h + CSR gather
        bf16t* h = (bf16t*)p; p += sz_hb;
        int* csr_src = (int*)p; p += sz_csr;
        int* rowptr = (int*)p; p += sz_row;
        int* deg = (int*)p; p += sz_deg;
        int* cursor = (int*)p; p += sz_cur;
        int* partials = (int*)p; p += sz_par;
        float* stats = (float*)p; p += sz_sta;
        float* gpool = (float*)p;
        run_pipeline<bf16t, true, false>(d_in, S, h, nullptr, csr_src, rowptr, deg, cursor,
                                         partials, stats, gpool, out, stream);
    } else {
        // tier C: bf16 h + atomic scatter (minimal footprint)
        bf16t* h = (bf16t*)p; p += sz_hb;
        float* stats = (float*)p; p += sz_sta;
        float* gpool = (float*)p;
        run_pipeline<bf16t, false, false>(d_in, S, h, nullptr, nullptr, nullptr, nullptr,
                                          nullptr, nullptr, stats, gpool, out, stream);
    }
}